// Round 1
// baseline (137.120 us; speedup 1.0000x reference)
//
#include <hip/hip_runtime.h>
#include <cstdint>
#include <cstddef>

#define BATCH   16384
#define NFEAT   2048
#define KD      1024     // num_used (= K of GEMM1, = rows of W)
#define NNODE   1024     // num_leaves / node columns
#define NCLS    100
#define NCP     128      // padded class count

typedef __attribute__((ext_vector_type(8))) __bf16 bf16x8;
typedef __attribute__((ext_vector_type(4))) float f32x4;
typedef __attribute__((ext_vector_type(4))) unsigned int u32x4;

__device__ __forceinline__ unsigned short f2bf(float f) {
  union { float f; unsigned int u; } v; v.f = f;
  unsigned int r = v.u + 0x7FFFu + ((v.u >> 16) & 1u);
  return (unsigned short)(r >> 16);
}
__device__ __forceinline__ float bf2f(unsigned short h) {
  union { unsigned int u; float f; } v; v.u = ((unsigned int)h) << 16;
  return v.f;
}

__device__ __forceinline__ void gload_lds16(const void* g, void* l) {
  __builtin_amdgcn_global_load_lds((__attribute__((address_space(1))) void*)g,
                                   (__attribute__((address_space(3))) void*)l,
                                   16, 0, 0);
}

// ---- prep: extract idx[i] = argmax of one-hot mask row i ----
__global__ void k_idx(const float* __restrict__ mask, int* __restrict__ idx) {
  int r = blockIdx.x, t = threadIdx.x;
  for (int c = t; c < NFEAT; c += 256)
    if (mask[(size_t)r * NFEAT + c] > 0.5f) idx[r] = c;
}

// ---- prep: WT[n][k] = bf16(W[k][n]) ----
__global__ void k_wt(const float* __restrict__ W, unsigned short* __restrict__ WT) {
  __shared__ float tile[32][33];
  int n0 = blockIdx.x * 32, k0 = blockIdx.y * 32;
  int tx = threadIdx.x, ty = threadIdx.y; // (32, 8)
  for (int i = ty; i < 32; i += 8)
    tile[i][tx] = W[(size_t)(k0 + i) * NNODE + n0 + tx];
  __syncthreads();
  for (int i = ty; i < 32; i += 8)
    WT[(size_t)(n0 + i) * KD + k0 + tx] = f2bf(tile[tx][i]);
}

// ---- prep: PT[n][l] = bf16(softmax(pi[l,:])[n]), zero-padded to NCP rows ----
__global__ void k_probs(const float* __restrict__ pi, unsigned short* __restrict__ PT) {
  int l = blockIdx.x, t = threadIdx.x; // 64 threads
  float v0 = (t < NCLS) ? pi[(size_t)l * NCLS + t] : -1e30f;
  float v1 = (t + 64 < NCLS) ? pi[(size_t)l * NCLS + t + 64] : -1e30f;
  float m = fmaxf(v0, v1);
  for (int o = 32; o; o >>= 1) m = fmaxf(m, __shfl_xor(m, o));
  float e0 = (t < NCLS) ? __expf(v0 - m) : 0.f;
  float e1 = (t + 64 < NCLS) ? __expf(v1 - m) : 0.f;
  float s = e0 + e1;
  for (int o = 32; o; o >>= 1) s += __shfl_xor(s, o);
  float inv = 1.f / s;
  PT[(size_t)t * NNODE + l] = f2bf(e0 * inv);
  PT[(size_t)(t + 64) * NNODE + l] = f2bf(e1 * inv);
}

// ---- gather: X[b][i] = bf16(features[b][idx[i]]) ----
__global__ void k_gather(const float* __restrict__ F, const int* __restrict__ idx,
                         unsigned short* __restrict__ X) {
  __shared__ int idxs[KD];
  int b = blockIdx.x, t = threadIdx.x;
  for (int j = t; j < KD; j += 256) idxs[j] = idx[j];
  __syncthreads();
  const float* row = F + (size_t)b * NFEAT;
  int i0 = t * 4;
  ushort4 o;
  o.x = f2bf(row[idxs[i0 + 0]]);
  o.y = f2bf(row[idxs[i0 + 1]]);
  o.z = f2bf(row[idxs[i0 + 2]]);
  o.w = f2bf(row[idxs[i0 + 3]]);
  *(ushort4*)(X + (size_t)b * KD + i0) = o;
}

// ---- MFMA GEMM: C[M][N] = A[M][K] * Bt[N][K]^T, 128x128 tile, BK=64 ----
// EPI==1: outBf[m][n] = bf16(sigmoid(C + bias[n])), N=1024
// EPI==2: outF[m][n]  = C for n < NCLS, row stride NCLS
template <int EPI>
__global__ __launch_bounds__(256)
void k_gemm(const unsigned short* __restrict__ A, const unsigned short* __restrict__ Bt,
            const float* __restrict__ bias, unsigned short* __restrict__ outBf,
            float* __restrict__ outF) {
  __shared__ __align__(16) unsigned short As[128 * 64];
  __shared__ __align__(16) unsigned short Bs[128 * 64];
  const int t = threadIdx.x;
  const int lane = t & 63;
  const int wave = t >> 6;
  const int m0 = blockIdx.x * 128;
  const int n0 = blockIdx.y * 128;
  const int wm = (wave >> 1) * 64;
  const int wn = (wave & 1) * 64;
  const int kg = t & 7;

  f32x4 acc[4][4];
#pragma unroll
  for (int i = 0; i < 4; ++i)
#pragma unroll
    for (int j = 0; j < 4; ++j) acc[i][j] = (f32x4)0.f;

  for (int kt = 0; kt < KD / 64; ++kt) {
    const int k0 = kt * 64;
#pragma unroll
    for (int j = 0; j < 4; ++j) {
      int row = j * 32 + (t >> 3);
      const unsigned short* ga = A + (size_t)(m0 + row) * KD + k0 + kg * 8;
      unsigned short* la = As + (size_t)(j * 256 + (t & ~63)) * 8;
      gload_lds16(ga, la);
      const unsigned short* gb = Bt + (size_t)(n0 + row) * KD + k0 + kg * 8;
      unsigned short* lb = Bs + (size_t)(j * 256 + (t & ~63)) * 8;
      gload_lds16(gb, lb);
    }
    __syncthreads();
#pragma unroll
    for (int kk = 0; kk < 2; ++kk) {
      bf16x8 af[4], bfr[4];
      const int kl = kk * 32 + (lane >> 4) * 8;
#pragma unroll
      for (int m = 0; m < 4; ++m) {
        int row = wm + m * 16 + (lane & 15);
        af[m] = __builtin_bit_cast(bf16x8, *(const u32x4*)(As + row * 64 + kl));
      }
#pragma unroll
      for (int n = 0; n < 4; ++n) {
        int col = wn + n * 16 + (lane & 15);
        bfr[n] = __builtin_bit_cast(bf16x8, *(const u32x4*)(Bs + col * 64 + kl));
      }
#pragma unroll
      for (int m = 0; m < 4; ++m)
#pragma unroll
        for (int n = 0; n < 4; ++n)
          acc[m][n] = __builtin_amdgcn_mfma_f32_16x16x32_bf16(af[m], bfr[n], acc[m][n], 0, 0, 0);
    }
    __syncthreads();
  }

  const int cl = lane & 15;
  const int rq = lane >> 4;
  if (EPI == 1) {
#pragma unroll
    for (int n = 0; n < 4; ++n) {
      int col = n0 + wn + n * 16 + cl;
      float bv = bias[col];
#pragma unroll
      for (int m = 0; m < 4; ++m) {
        int rbase = m0 + wm + m * 16 + rq * 4;
#pragma unroll
        for (int i = 0; i < 4; ++i) {
          float v = acc[m][n][i] + bv;
          float s = 1.0f / (1.0f + __expf(-v));
          outBf[(size_t)(rbase + i) * NNODE + col] = f2bf(s);
        }
      }
    }
  } else {
#pragma unroll
    for (int n = 0; n < 4; ++n) {
      int col = n0 + wn + n * 16 + cl;
      if (col < NCLS) {
#pragma unroll
        for (int m = 0; m < 4; ++m) {
          int rbase = m0 + wm + m * 16 + rq * 4;
#pragma unroll
          for (int i = 0; i < 4; ++i)
            outF[(size_t)(rbase + i) * NCLS + col] = acc[m][n][i];
        }
      }
    }
  }
}

// ---- tree routing: in-place D row (d values) -> mu values ----
__global__ void k_route(unsigned short* __restrict__ D) {
  __shared__ float dsh[NNODE];
  int b = blockIdx.x, t = threadIdx.x;
  unsigned short* row = D + (size_t)b * NNODE;
  ushort4 v = *(const ushort4*)(row + t * 4);
  dsh[t * 4 + 0] = bf2f(v.x);
  dsh[t * 4 + 1] = bf2f(v.y);
  dsh[t * 4 + 2] = bf2f(v.z);
  dsh[t * 4 + 3] = bf2f(v.w);
  __syncthreads();
  ushort4 o;
  unsigned short* op = (unsigned short*)&o;
#pragma unroll
  for (int j = 0; j < 4; ++j) {
    int l = t * 4 + j;
    float p = 1.0f;
#pragma unroll
    for (int k = 0; k < 10; ++k) {
      int node = (1 << k) + (l >> (10 - k));
      float dv = dsh[node];
      p *= ((l >> (9 - k)) & 1) ? (1.0f - dv) : dv;
    }
    op[j] = f2bf(p);
  }
  *(ushort4*)(row + t * 4) = o;
}

extern "C" void kernel_launch(void* const* d_in, const int* in_sizes, int n_in,
                              void* d_out, int out_size, void* d_ws, size_t ws_size,
                              hipStream_t stream) {
  const float* features = (const float*)d_in[0]; // [16384][2048]
  const float* mask     = (const float*)d_in[1]; // [1024][2048]
  const float* W        = (const float*)d_in[2]; // [1024][1024]
  const float* bias     = (const float*)d_in[3]; // [1024]
  const float* pi       = (const float*)d_in[4]; // [1024][100]
  float* out = (float*)d_out;                    // [16384][100]

  char* ws = (char*)d_ws;
  int* idx           = (int*)ws;                                    // 4 KiB
  unsigned short* WT = (unsigned short*)(ws + 4096);                // 2 MiB [1024][1024]
  unsigned short* PT = (unsigned short*)(ws + 4096 + (1u << 21));   // 256 KiB [128][1024]
  unsigned short* X  = (unsigned short*)(ws + 4096 + (1u << 21) + (1u << 18)); // 32 MiB
  unsigned short* D  = (unsigned short*)(ws + 4096 + (1u << 21) + (1u << 18) + (1u << 25)); // 32 MiB

  k_idx<<<dim3(KD), dim3(256), 0, stream>>>(mask, idx);
  k_wt<<<dim3(32, 32), dim3(32, 8), 0, stream>>>(W, WT);
  k_probs<<<dim3(NNODE), dim3(64), 0, stream>>>(pi, PT);
  k_gather<<<dim3(BATCH), dim3(256), 0, stream>>>(features, idx, X);
  k_gemm<1><<<dim3(BATCH / 128, NNODE / 128), dim3(256), 0, stream>>>(X, WT, bias, D, nullptr);
  k_route<<<dim3(BATCH), dim3(256), 0, stream>>>(D);
  k_gemm<2><<<dim3(BATCH / 128, 1), dim3(256), 0, stream>>>(D, PT, nullptr, nullptr, out);
}

// Round 2
// 118.681 us; speedup vs baseline: 1.1554x; 1.1554x over previous
//
#include <hip/hip_runtime.h>
#include <cstdint>
#include <cstddef>

#define BATCH   16384
#define NFEAT   2048
#define KD      1024     // num_used (= K of GEMM1, = rows of W)
#define NNODE   1024     // num_leaves / node columns
#define NCLS    100

typedef __attribute__((ext_vector_type(8))) __bf16 bf16x8;
typedef __attribute__((ext_vector_type(4))) float f32x4;
typedef __attribute__((ext_vector_type(4))) unsigned int u32x4;

__device__ __forceinline__ unsigned short f2bf(float f) {
  union { float f; unsigned int u; } v; v.f = f;
  unsigned int r = v.u + 0x7FFFu + ((v.u >> 16) & 1u);
  return (unsigned short)(r >> 16);
}
__device__ __forceinline__ float bf2f(unsigned short h) {
  union { unsigned int u; float f; } v; v.u = ((unsigned int)h) << 16;
  return v.f;
}

__device__ __forceinline__ void gload_lds16(const void* g, void* l) {
  __builtin_amdgcn_global_load_lds((__attribute__((address_space(1))) void*)g,
                                   (__attribute__((address_space(3))) void*)l,
                                   16, 0, 0);
}

__device__ __forceinline__ bf16x8 ld_frag(const unsigned short* p) {
  return __builtin_bit_cast(bf16x8, *(const u32x4*)p);
}

// ---- prep: extract idx[i] = argmax of one-hot mask row i ----
__global__ void k_idx(const float* __restrict__ mask, int* __restrict__ idx) {
  int r = blockIdx.x, t = threadIdx.x;
  for (int c = t; c < NFEAT; c += 256)
    if (mask[(size_t)r * NFEAT + c] > 0.5f) idx[r] = c;
}

// ---- prep: WT[n][k] = bf16(W[k][n]) ----
__global__ void k_wt(const float* __restrict__ W, unsigned short* __restrict__ WT) {
  __shared__ float tile[32][33];
  int n0 = blockIdx.x * 32, k0 = blockIdx.y * 32;
  int tx = threadIdx.x, ty = threadIdx.y; // (32, 8)
  for (int i = ty; i < 32; i += 8)
    tile[i][tx] = W[(size_t)(k0 + i) * NNODE + n0 + tx];
  __syncthreads();
  for (int i = ty; i < 32; i += 8)
    WT[(size_t)(n0 + i) * KD + k0 + tx] = f2bf(tile[tx][i]);
}

// ---- prep: PT[n][l] = bf16(softmax(pi[l,:])[n]), zero-padded to 128 rows ----
__global__ void k_probs(const float* __restrict__ pi, unsigned short* __restrict__ PT) {
  int l = blockIdx.x, t = threadIdx.x; // 64 threads
  float v0 = (t < NCLS) ? pi[(size_t)l * NCLS + t] : -1e30f;
  float v1 = (t + 64 < NCLS) ? pi[(size_t)l * NCLS + t + 64] : -1e30f;
  float m = fmaxf(v0, v1);
  for (int o = 32; o; o >>= 1) m = fmaxf(m, __shfl_xor(m, o));
  float e0 = (t < NCLS) ? __expf(v0 - m) : 0.f;
  float e1 = (t + 64 < NCLS) ? __expf(v1 - m) : 0.f;
  float s = e0 + e1;
  for (int o = 32; o; o >>= 1) s += __shfl_xor(s, o);
  float inv = 1.f / s;
  PT[(size_t)t * NNODE + l] = f2bf(e0 * inv);
  PT[(size_t)(t + 64) * NNODE + l] = f2bf(e1 * inv);
}

// ---- gather: X[b][i] = bf16(features[b][idx[i]]) ----
__global__ void k_gather(const float* __restrict__ F, const int* __restrict__ idx,
                         unsigned short* __restrict__ X) {
  __shared__ int idxs[KD];
  int b = blockIdx.x, t = threadIdx.x;
  for (int j = t; j < KD; j += 256) idxs[j] = idx[j];
  __syncthreads();
  const float* row = F + (size_t)b * NFEAT;
  int i0 = t * 4;
  ushort4 o;
  o.x = f2bf(row[idxs[i0 + 0]]);
  o.y = f2bf(row[idxs[i0 + 1]]);
  o.z = f2bf(row[idxs[i0 + 2]]);
  o.w = f2bf(row[idxs[i0 + 3]]);
  *(ushort4*)(X + (size_t)b * KD + i0) = o;
}

// ============ GEMM1: D = sigmoid(X @ WT^T + b), 256x256 tile, BK=64 ============
// A = X [16384][1024] bf16, Bt = WT [1024][1024] bf16 (row n = col n of W).
// 512 threads = 8 waves (2M x 4N), wave tile 128x64, acc 8x4 frags.
// LDS: 4 x 32 KiB = 128 KiB, double-buffered, swizzled (col16 ^= row&7 via source).

// stage a 256x64 bf16 panel (rows row0.., cols k0..k0+63) into lds (linear,
// source pre-swizzled so that LDS[r][cb] = G[r][cb ^ ((r&7)<<4)]).
__device__ __forceinline__ void stage256(const unsigned short* __restrict__ G,
                                         int row0, int k0, unsigned short* lds, int t) {
  const int r = t >> 3;                       // 0..63
  const int c8 = ((t & 7) ^ (r & 7)) * 8;     // swizzled col (elems)
#pragma unroll
  for (int s = 0; s < 4; ++s)
    gload_lds16(G + (size_t)(row0 + s * 64 + r) * KD + k0 + c8,
                lds + s * 4096 + (t & ~63) * 8);
}

__device__ __forceinline__ void compute_ktile(const unsigned short* __restrict__ Asb,
                                              const unsigned short* __restrict__ Bsb,
                                              int lane, int wm, int wn,
                                              f32x4 (&acc)[8][4]) {
  const int rsel = (lane & 7) << 3;   // read-side swizzle (elems)
  const int klb = (lane >> 4) * 8;
  const int cl = lane & 15;
  bf16x8 bfrag[4][2], afrag[4][2];
#pragma unroll
  for (int n = 0; n < 4; ++n) {
    const unsigned short* p = Bsb + (wn + n * 16 + cl) * 64;
#pragma unroll
    for (int kk = 0; kk < 2; ++kk)
      bfrag[n][kk] = ld_frag(p + ((kk * 32 + klb) ^ rsel));
  }
  // A low half (rows wm .. wm+63)
#pragma unroll
  for (int m = 0; m < 4; ++m) {
    const unsigned short* p = Asb + (wm + m * 16 + cl) * 64;
#pragma unroll
    for (int kk = 0; kk < 2; ++kk)
      afrag[m][kk] = ld_frag(p + ((kk * 32 + klb) ^ rsel));
  }
  __builtin_amdgcn_s_setprio(1);
#pragma unroll
  for (int m = 0; m < 4; ++m)
#pragma unroll
    for (int n = 0; n < 4; ++n)
#pragma unroll
      for (int kk = 0; kk < 2; ++kk)
        acc[m][n] = __builtin_amdgcn_mfma_f32_16x16x32_bf16(afrag[m][kk], bfrag[n][kk], acc[m][n], 0, 0, 0);
  __builtin_amdgcn_s_setprio(0);
  // A high half (rows wm+64 .. wm+127)
#pragma unroll
  for (int m = 0; m < 4; ++m) {
    const unsigned short* p = Asb + (wm + 64 + m * 16 + cl) * 64;
#pragma unroll
    for (int kk = 0; kk < 2; ++kk)
      afrag[m][kk] = ld_frag(p + ((kk * 32 + klb) ^ rsel));
  }
  __builtin_amdgcn_s_setprio(1);
#pragma unroll
  for (int m = 0; m < 4; ++m)
#pragma unroll
    for (int n = 0; n < 4; ++n)
#pragma unroll
      for (int kk = 0; kk < 2; ++kk)
        acc[m + 4][n] = __builtin_amdgcn_mfma_f32_16x16x32_bf16(afrag[m][kk], bfrag[n][kk], acc[m + 4][n], 0, 0, 0);
  __builtin_amdgcn_s_setprio(0);
}

__global__ __launch_bounds__(512, 2)
void k_gemm1(const unsigned short* __restrict__ A, const unsigned short* __restrict__ Bt,
             const float* __restrict__ bias, unsigned short* __restrict__ D) {
  __shared__ __align__(16) unsigned short As0[256 * 64];
  __shared__ __align__(16) unsigned short Bs0[256 * 64];
  __shared__ __align__(16) unsigned short As1[256 * 64];
  __shared__ __align__(16) unsigned short Bs1[256 * 64];
  const int t = threadIdx.x;
  const int lane = t & 63;
  const int wave = t >> 6;
  const int m0 = blockIdx.x * 256;
  const int n0 = blockIdx.y * 256;
  const int wm = (wave >> 2) * 128;
  const int wn = (wave & 3) * 64;

  f32x4 acc[8][4];
#pragma unroll
  for (int i = 0; i < 8; ++i)
#pragma unroll
    for (int j = 0; j < 4; ++j) acc[i][j] = (f32x4)0.f;

  stage256(A, m0, 0, As0, t);
  stage256(Bt, n0, 0, Bs0, t);
  __syncthreads();

  for (int kt2 = 0; kt2 < 8; ++kt2) {
    const int kt = kt2 * 2;
    // even body: compute buf0 (tile kt), prefetch tile kt+1 -> buf1
    stage256(A, m0, (kt + 1) * 64, As1, t);
    stage256(Bt, n0, (kt + 1) * 64, Bs1, t);
    compute_ktile(As0, Bs0, lane, wm, wn, acc);
    __syncthreads();   // drains vmcnt (tile kt+1 landed), lgkm; barrier
    // odd body: compute buf1 (tile kt+1), prefetch tile kt+2 -> buf0
    if (kt2 < 7) {
      stage256(A, m0, (kt + 2) * 64, As0, t);
      stage256(Bt, n0, (kt + 2) * 64, Bs0, t);
    }
    compute_ktile(As1, Bs1, lane, wm, wn, acc);
    __syncthreads();
  }

  // epilogue: sigmoid(acc + bias) -> bf16 D
  const int cl = lane & 15;
  const int rq = lane >> 4;
#pragma unroll
  for (int n = 0; n < 4; ++n) {
    const int col = n0 + wn + n * 16 + cl;
    const float bv = bias[col];
#pragma unroll
    for (int M = 0; M < 8; ++M) {
      const int rowb = m0 + wm + (M >> 2) * 64 + (M & 3) * 16 + rq * 4;
#pragma unroll
      for (int i = 0; i < 4; ++i) {
        float v = acc[M][n][i] + bv;
        float s = 1.0f / (1.0f + __expf(-v));
        D[(size_t)(rowb + i) * NNODE + col] = f2bf(s);
      }
    }
  }
}

// ============ GEMM2: out = mu @ PT^T (128x128 tile, old structure) ============
__global__ __launch_bounds__(256)
void k_gemm2(const unsigned short* __restrict__ A, const unsigned short* __restrict__ Bt,
             float* __restrict__ outF) {
  __shared__ __align__(16) unsigned short As[128 * 64];
  __shared__ __align__(16) unsigned short Bs[128 * 64];
  const int t = threadIdx.x;
  const int lane = t & 63;
  const int wave = t >> 6;
  const int m0 = blockIdx.x * 128;
  const int n0 = 0;
  const int wm = (wave >> 1) * 64;
  const int wn = (wave & 1) * 64;
  const int kg = t & 7;

  f32x4 acc[4][4];
#pragma unroll
  for (int i = 0; i < 4; ++i)
#pragma unroll
    for (int j = 0; j < 4; ++j) acc[i][j] = (f32x4)0.f;

  for (int kt = 0; kt < KD / 64; ++kt) {
    const int k0 = kt * 64;
#pragma unroll
    for (int j = 0; j < 4; ++j) {
      int row = j * 32 + (t >> 3);
      gload_lds16(A + (size_t)(m0 + row) * KD + k0 + kg * 8,
                  As + (size_t)(j * 256 + (t & ~63)) * 8);
      gload_lds16(Bt + (size_t)(n0 + row) * KD + k0 + kg * 8,
                  Bs + (size_t)(j * 256 + (t & ~63)) * 8);
    }
    __syncthreads();
#pragma unroll
    for (int kk = 0; kk < 2; ++kk) {
      bf16x8 af[4], bfr[4];
      const int kl = kk * 32 + (lane >> 4) * 8;
#pragma unroll
      for (int m = 0; m < 4; ++m)
        af[m] = ld_frag(As + (wm + m * 16 + (lane & 15)) * 64 + kl);
#pragma unroll
      for (int n = 0; n < 4; ++n)
        bfr[n] = ld_frag(Bs + (wn + n * 16 + (lane & 15)) * 64 + kl);
#pragma unroll
      for (int m = 0; m < 4; ++m)
#pragma unroll
        for (int n = 0; n < 4; ++n)
          acc[m][n] = __builtin_amdgcn_mfma_f32_16x16x32_bf16(af[m], bfr[n], acc[m][n], 0, 0, 0);
    }
    __syncthreads();
  }

  const int cl = lane & 15;
  const int rq = lane >> 4;
#pragma unroll
  for (int n = 0; n < 4; ++n) {
    int col = n0 + wn + n * 16 + cl;
    if (col < NCLS) {
#pragma unroll
      for (int m = 0; m < 4; ++m) {
        int rbase = m0 + wm + m * 16 + rq * 4;
#pragma unroll
        for (int i = 0; i < 4; ++i)
          outF[(size_t)(rbase + i) * NCLS + col] = acc[m][n][i];
      }
    }
  }
}

// ---- tree routing: in-place D row (d values) -> mu values ----
__global__ void k_route(unsigned short* __restrict__ D) {
  __shared__ float dsh[NNODE];
  int b = blockIdx.x, t = threadIdx.x;
  unsigned short* row = D + (size_t)b * NNODE;
  ushort4 v = *(const ushort4*)(row + t * 4);
  dsh[t * 4 + 0] = bf2f(v.x);
  dsh[t * 4 + 1] = bf2f(v.y);
  dsh[t * 4 + 2] = bf2f(v.z);
  dsh[t * 4 + 3] = bf2f(v.w);
  __syncthreads();
  ushort4 o;
  unsigned short* op = (unsigned short*)&o;
#pragma unroll
  for (int j = 0; j < 4; ++j) {
    int l = t * 4 + j;
    float p = 1.0f;
#pragma unroll
    for (int k = 0; k < 10; ++k) {
      int node = (1 << k) + (l >> (10 - k));
      float dv = dsh[node];
      p *= ((l >> (9 - k)) & 1) ? (1.0f - dv) : dv;
    }
    op[j] = f2bf(p);
  }
  *(ushort4*)(row + t * 4) = o;
}

extern "C" void kernel_launch(void* const* d_in, const int* in_sizes, int n_in,
                              void* d_out, int out_size, void* d_ws, size_t ws_size,
                              hipStream_t stream) {
  const float* features = (const float*)d_in[0]; // [16384][2048]
  const float* mask     = (const float*)d_in[1]; // [1024][2048]
  const float* W        = (const float*)d_in[2]; // [1024][1024]
  const float* bias     = (const float*)d_in[3]; // [1024]
  const float* pi       = (const float*)d_in[4]; // [1024][100]
  float* out = (float*)d_out;                    // [16384][100]

  char* ws = (char*)d_ws;
  int* idx           = (int*)ws;                                    // 4 KiB
  unsigned short* WT = (unsigned short*)(ws + 4096);                // 2 MiB [1024][1024]
  unsigned short* PT = (unsigned short*)(ws + 4096 + (1u << 21));   // 256 KiB [128][1024]
  unsigned short* X  = (unsigned short*)(ws + 4096 + (1u << 21) + (1u << 18)); // 32 MiB
  unsigned short* D  = (unsigned short*)(ws + 4096 + (1u << 21) + (1u << 18) + (1u << 25)); // 32 MiB

  k_idx<<<dim3(KD), dim3(256), 0, stream>>>(mask, idx);
  k_wt<<<dim3(32, 32), dim3(32, 8), 0, stream>>>(W, WT);
  k_probs<<<dim3(NNODE), dim3(64), 0, stream>>>(pi, PT);
  k_gather<<<dim3(BATCH), dim3(256), 0, stream>>>(features, idx, X);
  k_gemm1<<<dim3(BATCH / 256, NNODE / 256), dim3(512), 0, stream>>>(X, WT, bias, D);
  k_route<<<dim3(BATCH), dim3(256), 0, stream>>>(D);
  k_gemm2<<<dim3(BATCH / 128, 1), dim3(256), 0, stream>>>(D, PT, out);
}